// Round 1
// baseline (159.732 us; speedup 1.0000x reference)
//
#include <hip/hip_runtime.h>

typedef __bf16 bf16x8 __attribute__((ext_vector_type(8)));
typedef float f32x4 __attribute__((ext_vector_type(4)));
typedef unsigned int u32x4 __attribute__((ext_vector_type(4)));

__device__ __forceinline__ unsigned short f2bf(float f) {
  unsigned int u = __float_as_uint(f);
  u += 0x7FFFu + ((u >> 16) & 1u);   // round-to-nearest-even
  return (unsigned short)(u >> 16);
}

__device__ __forceinline__ bf16x8 load_frag(const unsigned short* p) {
  u32x4 v = *(const u32x4*)p;
  return __builtin_bit_cast(bf16x8, v);
}

// ---------------------------------------------------------------------------
// Convert all four used fp32 tensors to bf16 (object dims zero-padded to a
// multiple of 16 for MFMA M-tiling). Block ranges hardcoded:
//   im   : 128x36x128 -> 128x48x128   blocks [0,768)     (128*48*32 threads)
//   s    : 128x50x128 -> 128x50x128   blocks [768,1568)
//   pred : 128x25x128 -> 128x32x128   blocks [1568,2080)
//   crp  : 128x30x128 -> 128x30x128   blocks [2080,2560)
// ---------------------------------------------------------------------------
__global__ __launch_bounds__(256) void convert_all(
    const float* __restrict__ im, const float* __restrict__ s,
    const float* __restrict__ pred, const float* __restrict__ crp,
    unsigned short* __restrict__ imb, unsigned short* __restrict__ sb,
    unsigned short* __restrict__ pb, unsigned short* __restrict__ cb)
{
  int b = blockIdx.x;
  const float* src; unsigned short* dst; int O, OP, base;
  if (b < 768)       { src = im;   dst = imb; O = 36; OP = 48; base = 0; }
  else if (b < 1568) { src = s;    dst = sb;  O = 50; OP = 50; base = 768; }
  else if (b < 2080) { src = pred; dst = pb;  O = 25; OP = 32; base = 1568; }
  else               { src = crp;  dst = cb;  O = 30; OP = 30; base = 2080; }
  int tid = (b - base) * 256 + (int)threadIdx.x;          // one thread = 4 floats
  int total = 128 * OP * 32;
  if (tid >= total) return;
  int d4 = tid & 31;
  int o  = (tid >> 5) % OP;
  int bb = tid / (OP * 32);
  unsigned short r0 = 0, r1 = 0, r2 = 0, r3 = 0;
  if (o < O) {
    const float4 v = *(const float4*)(src + ((bb * O + o) << 7) + (d4 << 2));
    r0 = f2bf(v.x); r1 = f2bf(v.y); r2 = f2bf(v.z); r3 = f2bf(v.w);
  }
  ushort4 outv; outv.x = r0; outv.y = r1; outv.z = r2; outv.w = r3;
  *(ushort4*)(dst + (size_t)tid * 4) = outv;
}

// ---------------------------------------------------------------------------
// t2i pooled score. Block = (image i, caption group of CG=16).
// A (padded objects, MT 16-row tiles x K=128) held in registers per wave.
// B (words) streamed from global; each wave owns N-tiles nt = wv, wv+4, ...
// D fragment mapping (m89/m91-verified): col = lane&15 (word), row =
// (lane>>4)*4 + reg (object within tile).
// ---------------------------------------------------------------------------
template<int MT, int W>
__global__ __launch_bounds__(256) void t2i_kernel(
    const unsigned short* __restrict__ A,    // [128, MT*16, 128] bf16
    const unsigned short* __restrict__ Bw,   // [128, W, 128] bf16
    const int* __restrict__ obj_l, const int* __restrict__ cap_l,
    float* __restrict__ pooled)              // [128,128] fp32
{
  constexpr int CG = 16;
  constexpr int NT = CG * W / 16;            // 50 (term1) / 30 (term2), exact
  __shared__ float wmax[CG * W];
  const int i   = blockIdx.x;
  const int cg0 = blockIdx.y * CG;
  const int tid = threadIdx.x;
  const int wv = tid >> 6, lane = tid & 63;
  const int quad = lane >> 4, n16 = lane & 15;
  const int obj_li = obj_l[i];

  // Load A fragments: af[t][s] covers rows t*16..t*16+15, k = s*32..s*32+31.
  bf16x8 af[MT][4];
  const unsigned short* Abase = A + (((size_t)i * (MT * 16) + n16) << 7) + quad * 8;
#pragma unroll
  for (int t = 0; t < MT; ++t)
#pragma unroll
    for (int s = 0; s < 4; ++s)
      af[t][s] = load_frag(Abase + ((t * 16) << 7) + s * 32);

  const unsigned short* Bbase = Bw + (((size_t)cg0 * W + n16) << 7) + quad * 8;

  for (int nt = wv; nt < NT; nt += 4) {
    const unsigned short* bp = Bbase + ((nt * 16) << 7);
    bf16x8 bfrag[4];
#pragma unroll
    for (int s = 0; s < 4; ++s) bfrag[s] = load_frag(bp + s * 32);

    f32x4 acc[MT];
#pragma unroll
    for (int t = 0; t < MT; ++t) { f32x4 z = {0.f, 0.f, 0.f, 0.f}; acc[t] = z; }
#pragma unroll
    for (int s = 0; s < 4; ++s)
#pragma unroll
      for (int t = 0; t < MT; ++t)
        acc[t] = __builtin_amdgcn_mfma_f32_16x16x32_bf16(af[t][s], bfrag[s], acc[t], 0, 0, 0);

    // max over valid objects for this lane's word column
    float m = -3.0e38f;
#pragma unroll
    for (int t = 0; t < MT; ++t)
#pragma unroll
      for (int r = 0; r < 4; ++r) {
        int o = t * 16 + quad * 4 + r;
        if (o < obj_li) m = fmaxf(m, acc[t][r]);
      }
    m = fmaxf(m, __shfl_xor(m, 16));
    m = fmaxf(m, __shfl_xor(m, 32));
    if (quad == 0) wmax[nt * 16 + n16] = m;
  }
  __syncthreads();

  // segment sum per caption, normalize by caption length
  if (tid < CG) {
    float ssum = 0.f;
    const float* wp = wmax + tid * W;
    for (int w = 0; w < W; ++w) ssum += wp[w];
    int c = cg0 + tid;
    pooled[(i << 7) + c] = ssum / (float)cap_l[c];
  }
}

// ---------------------------------------------------------------------------
// Hinge loss over the 128x128 score matrix. One block, 256 threads:
// threads [0,128) do row-maxes (cost_s), [128,256) do col-maxes (cost_im).
// ---------------------------------------------------------------------------
__global__ __launch_bounds__(256) void loss_kernel(
    const float* __restrict__ p1, const float* __restrict__ p2,
    float* __restrict__ out)
{
  __shared__ float diag[128];
  __shared__ float red[256];
  const int t = threadIdx.x;
  if (t < 128) diag[t] = p1[t * 128 + t] + p2[t * 128 + t];
  __syncthreads();

  float partial = 0.f;
  if (t < 128) {
    const int i = t;
    const float di = diag[i];
    float m = 0.f;                       // clamped costs are >= 0; diag forced 0
    for (int j = 0; j < 128; ++j) {
      if (j == i) continue;
      float sc = p1[i * 128 + j] + p2[i * 128 + j];
      m = fmaxf(m, 0.2f + sc - di);
    }
    partial = m;
  } else {
    const int j = t - 128;
    const float dj = diag[j];
    float m = 0.f;
    for (int i = 0; i < 128; ++i) {
      if (i == j) continue;
      float sc = p1[i * 128 + j] + p2[i * 128 + j];
      m = fmaxf(m, 0.2f + sc - dj);
    }
    partial = m;
  }
  red[t] = partial;
  __syncthreads();
  for (int st = 128; st > 0; st >>= 1) {
    if (t < st) red[t] += red[t + st];
    __syncthreads();
  }
  if (t == 0) out[0] = red[0];
}

// ---------------------------------------------------------------------------
extern "C" void kernel_launch(void* const* d_in, const int* in_sizes, int n_in,
                              void* d_out, int out_size, void* d_ws, size_t ws_size,
                              hipStream_t stream)
{
  const float* im     = (const float*)d_in[0];
  const int*   im_l   = (const int*)  d_in[1];
  const float* s      = (const float*)d_in[2];
  const int*   s_l    = (const int*)  d_in[3];
  const float* pred   = (const float*)d_in[4];
  const int*   pred_l = (const int*)  d_in[5];
  // d_in[6], d_in[7] (cap_o_pred, cap_o_l) are unused by the reference.
  const float* crp    = (const float*)d_in[8];
  const int*   crl    = (const int*)  d_in[9];

  char* ws = (char*)d_ws;
  const size_t off_imb = 0;
  const size_t off_sb  = off_imb + (size_t)128 * 48 * 128 * 2;   // 1572864
  const size_t off_pb  = off_sb  + (size_t)128 * 50 * 128 * 2;   // +1638400
  const size_t off_cb  = off_pb  + (size_t)128 * 32 * 128 * 2;   // +1048576
  const size_t off_p1  = off_cb  + (size_t)128 * 30 * 128 * 2;   // +983040
  const size_t off_p2  = off_p1  + (size_t)128 * 128 * 4;

  unsigned short* imb = (unsigned short*)(ws + off_imb);
  unsigned short* sb  = (unsigned short*)(ws + off_sb);
  unsigned short* pb  = (unsigned short*)(ws + off_pb);
  unsigned short* cb  = (unsigned short*)(ws + off_cb);
  float* p1 = (float*)(ws + off_p1);
  float* p2 = (float*)(ws + off_p2);

  hipLaunchKernelGGL(convert_all, dim3(2560), dim3(256), 0, stream,
                     im, s, pred, crp, imb, sb, pb, cb);
  hipLaunchKernelGGL((t2i_kernel<3, 50>), dim3(128, 8), dim3(256), 0, stream,
                     imb, sb, im_l, s_l, p1);
  hipLaunchKernelGGL((t2i_kernel<2, 30>), dim3(128, 8), dim3(256), 0, stream,
                     pb, cb, pred_l, crl, p2);
  hipLaunchKernelGGL(loss_kernel, dim3(1), dim3(256), 0, stream,
                     p1, p2, (float*)d_out);
}

// Round 3
// 120.604 us; speedup vs baseline: 1.3244x; 1.3244x over previous
//
#include <hip/hip_runtime.h>

typedef __bf16 bf16x8 __attribute__((ext_vector_type(8)));
typedef float f32x4 __attribute__((ext_vector_type(4)));
typedef unsigned int u32x4 __attribute__((ext_vector_type(4)));

__device__ __forceinline__ unsigned short f2bf(float f) {
  unsigned int u = __float_as_uint(f);
  u += 0x7FFFu + ((u >> 16) & 1u);   // round-to-nearest-even
  return (unsigned short)(u >> 16);
}

__device__ __forceinline__ bf16x8 load_frag(const unsigned short* p) {
  u32x4 v = *(const u32x4*)p;
  return __builtin_bit_cast(bf16x8, v);
}

// ---------------------------------------------------------------------------
// Convert all four used fp32 tensors to bf16 (object dims zero-padded to a
// multiple of 16 for MFMA M-tiling). Verified in R1.
// ---------------------------------------------------------------------------
__global__ __launch_bounds__(256) void convert_all(
    const float* __restrict__ im, const float* __restrict__ s,
    const float* __restrict__ pred, const float* __restrict__ crp,
    unsigned short* __restrict__ imb, unsigned short* __restrict__ sb,
    unsigned short* __restrict__ pb, unsigned short* __restrict__ cb)
{
  int b = blockIdx.x;
  const float* src; unsigned short* dst; int O, OP, base;
  if (b < 768)       { src = im;   dst = imb; O = 36; OP = 48; base = 0; }
  else if (b < 1568) { src = s;    dst = sb;  O = 50; OP = 50; base = 768; }
  else if (b < 2080) { src = pred; dst = pb;  O = 25; OP = 32; base = 1568; }
  else               { src = crp;  dst = cb;  O = 30; OP = 30; base = 2080; }
  int tid = (b - base) * 256 + (int)threadIdx.x;          // one thread = 4 floats
  int total = 128 * OP * 32;
  if (tid >= total) return;
  int d4 = tid & 31;
  int o  = (tid >> 5) % OP;
  int bb = tid / (OP * 32);
  unsigned short r0 = 0, r1 = 0, r2 = 0, r3 = 0;
  if (o < O) {
    const float4 v = *(const float4*)(src + ((bb * O + o) << 7) + (d4 << 2));
    r0 = f2bf(v.x); r1 = f2bf(v.y); r2 = f2bf(v.z); r3 = f2bf(v.w);
  }
  ushort4 outv; outv.x = r0; outv.y = r1; outv.z = r2; outv.w = r3;
  *(ushort4*)(dst + (size_t)tid * 4) = outv;
}

// ---------------------------------------------------------------------------
// t2i pooled score, TWO images per block vs one 16-caption group (halves B
// L2 traffic vs R1). Same verified D mapping: col=lane&15 (B-row), row=
// (lane>>4)*4+reg (object).
// ---------------------------------------------------------------------------
template<int MT, int W>
__device__ __forceinline__ void t2i_im2(
    const unsigned short* __restrict__ A,    // [128, MT*16, 128] bf16
    const unsigned short* __restrict__ Bw,   // [128, W, 128] bf16
    const int* __restrict__ obj_l, const int* __restrict__ cap_l,
    float* __restrict__ pooled,              // [128,128] fp32
    int vb, float* wmax)                     // wmax LDS >= 2*16*W
{
  const int ig  = vb >> 3;             // 0..63 -> images 2*ig, 2*ig+1
  const int i0  = ig * 2;
  const int cg0 = (vb & 7) * 16;
  const int tid = threadIdx.x;
  const int wv = tid >> 6, lane = tid & 63;
  const int quad = lane >> 4, n16 = lane & 15;
  const int ol0 = obj_l[i0], ol1 = obj_l[i0 + 1];

  bf16x8 af[2][MT][4];
#pragma unroll
  for (int im = 0; im < 2; ++im) {
    const unsigned short* Ab =
        A + (((size_t)(i0 + im) * (MT * 16) + n16) << 7) + quad * 8;
#pragma unroll
    for (int t = 0; t < MT; ++t)
#pragma unroll
      for (int s = 0; s < 4; ++s)
        af[im][t][s] = load_frag(Ab + ((t * 16) << 7) + s * 32);
  }

  const unsigned short* Bbase = Bw + (((size_t)cg0 * W + n16) << 7) + quad * 8;

  for (int nt = wv; nt < W; nt += 4) {     // NT = 16*W/16 = W tiles, exact
    const unsigned short* bp = Bbase + ((nt * 16) << 7);
    bf16x8 bfrag[4];
#pragma unroll
    for (int s = 0; s < 4; ++s) bfrag[s] = load_frag(bp + s * 32);

    f32x4 acc[2][MT];
#pragma unroll
    for (int im = 0; im < 2; ++im)
#pragma unroll
      for (int t = 0; t < MT; ++t) { f32x4 z = {0.f,0.f,0.f,0.f}; acc[im][t] = z; }
#pragma unroll
    for (int s = 0; s < 4; ++s)
#pragma unroll
      for (int im = 0; im < 2; ++im)
#pragma unroll
        for (int t = 0; t < MT; ++t)
          acc[im][t] = __builtin_amdgcn_mfma_f32_16x16x32_bf16(
              af[im][t][s], bfrag[s], acc[im][t], 0, 0, 0);

#pragma unroll
    for (int im = 0; im < 2; ++im) {
      const int ol = im ? ol1 : ol0;
      float m = -3.0e38f;
#pragma unroll
      for (int t = 0; t < MT; ++t)
#pragma unroll
        for (int r = 0; r < 4; ++r) {
          int o = t * 16 + quad * 4 + r;
          if (o < ol) m = fmaxf(m, acc[im][t][r]);
        }
      m = fmaxf(m, __shfl_xor(m, 16));
      m = fmaxf(m, __shfl_xor(m, 32));
      if (quad == 0) wmax[im * (16 * W) + nt * 16 + n16] = m;
    }
  }
  __syncthreads();

  if (tid < 32) {
    const int im = tid >> 4, c = tid & 15;
    const float* wp = wmax + im * (16 * W) + c * W;
    float ssum = 0.f;
    for (int w = 0; w < W; ++w) ssum += wp[w];
    const int cc = cg0 + c;
    pooled[((i0 + im) << 7) + cc] = ssum / (float)cap_l[cc];
  }
}

__global__ __launch_bounds__(256) void t2i_both(
    const unsigned short* __restrict__ imb, const unsigned short* __restrict__ sb,
    const unsigned short* __restrict__ pb,  const unsigned short* __restrict__ cb,
    const int* __restrict__ im_l, const int* __restrict__ s_l,
    const int* __restrict__ pred_l, const int* __restrict__ crl,
    float* __restrict__ p1, float* __restrict__ p2)
{
  __shared__ float wmax[2 * 16 * 50];
  if (blockIdx.x < 512) t2i_im2<3, 50>(imb, sb, im_l, s_l, p1, blockIdx.x, wmax);
  else                  t2i_im2<2, 30>(pb, cb, pred_l, crl, p2, blockIdx.x - 512, wmax);
}

// ---------------------------------------------------------------------------
// Hinge loss, one block of 1024 threads, fully coalesced: thread (sub,j)
// scans 16 rows (j contiguous), computing row-hinge (diag[row]) and
// col-hinge (diag[j]) from the same load. Row max: wave shfl + LDS
// atomicMax on float bits (valid: hinges >= 0). Col max: register + LDS tree.
// ---------------------------------------------------------------------------
__global__ __launch_bounds__(1024) void loss_kernel(
    const float* __restrict__ p1, const float* __restrict__ p2,
    float* __restrict__ out)
{
  __shared__ float diag[128];
  __shared__ int   rowmaxi[128];
  __shared__ float colmax[8][128];
  __shared__ float wred[16];
  const int tid = threadIdx.x;
  const int sub = tid >> 7, j = tid & 127;
  if (sub == 0) {
    diag[j] = p1[j * 129] + p2[j * 129];
    rowmaxi[j] = 0;                         // float bits of 0.0f
  }
  __syncthreads();

  float colp = 0.f;
#pragma unroll
  for (int rr = 0; rr < 16; ++rr) {
    const int row = sub * 16 + rr;
    const float sc = p1[row * 128 + j] + p2[row * 128 + j];
    const float dr = diag[row];
    float rh = (j == row) ? 0.f : fmaxf(0.2f + sc - dr, 0.f);
    const float ch = (j == row) ? 0.f : fmaxf(0.2f + sc - diag[j], 0.f);
    colp = fmaxf(colp, ch);
#pragma unroll
    for (int o = 32; o; o >>= 1) rh = fmaxf(rh, __shfl_xor(rh, o));
    if ((tid & 63) == 0) atomicMax(&rowmaxi[row], __float_as_int(rh));
  }
  colmax[sub][j] = colp;
  __syncthreads();
  if (sub < 4) colmax[sub][j] = fmaxf(colmax[sub][j], colmax[sub + 4][j]);
  __syncthreads();
  if (sub < 2) colmax[sub][j] = fmaxf(colmax[sub][j], colmax[sub + 2][j]);
  __syncthreads();
  if (sub < 1) colmax[0][j] = fmaxf(colmax[0][j], colmax[1][j]);
  __syncthreads();

  float v = 0.f;
  if (tid < 128)      v = __int_as_float(rowmaxi[tid]);
  else if (tid < 256) v = colmax[0][tid - 128];
#pragma unroll
  for (int o = 32; o; o >>= 1) v += __shfl_xor(v, o);
  if ((tid & 63) == 0) wred[tid >> 6] = v;
  __syncthreads();
  if (tid == 0) {
    float sfin = 0.f;
    for (int k = 0; k < 16; ++k) sfin += wred[k];
    out[0] = sfin;
  }
}

// ---------------------------------------------------------------------------
extern "C" void kernel_launch(void* const* d_in, const int* in_sizes, int n_in,
                              void* d_out, int out_size, void* d_ws, size_t ws_size,
                              hipStream_t stream)
{
  const float* im     = (const float*)d_in[0];
  const int*   im_l   = (const int*)  d_in[1];
  const float* s      = (const float*)d_in[2];
  const int*   s_l    = (const int*)  d_in[3];
  const float* pred   = (const float*)d_in[4];
  const int*   pred_l = (const int*)  d_in[5];
  // d_in[6], d_in[7] unused by the reference.
  const float* crp    = (const float*)d_in[8];
  const int*   crl    = (const int*)  d_in[9];

  char* ws = (char*)d_ws;
  const size_t off_imb = 0;
  const size_t off_sb  = off_imb + (size_t)128 * 48 * 128 * 2;
  const size_t off_pb  = off_sb  + (size_t)128 * 50 * 128 * 2;
  const size_t off_cb  = off_pb  + (size_t)128 * 32 * 128 * 2;
  const size_t off_p1  = off_cb  + (size_t)128 * 30 * 128 * 2;
  const size_t off_p2  = off_p1  + (size_t)128 * 128 * 4;

  unsigned short* imb = (unsigned short*)(ws + off_imb);
  unsigned short* sb  = (unsigned short*)(ws + off_sb);
  unsigned short* pb  = (unsigned short*)(ws + off_pb);
  unsigned short* cb  = (unsigned short*)(ws + off_cb);
  float* p1 = (float*)(ws + off_p1);
  float* p2 = (float*)(ws + off_p2);

  hipLaunchKernelGGL(convert_all, dim3(2560), dim3(256), 0, stream,
                     im, s, pred, crp, imb, sb, pb, cb);
  hipLaunchKernelGGL(t2i_both, dim3(1024), dim3(256), 0, stream,
                     imb, sb, pb, cb, im_l, s_l, pred_l, crl, p1, p2);
  hipLaunchKernelGGL(loss_kernel, dim3(1), dim3(1024), 0, stream,
                     p1, p2, (float*)d_out);
}